// Round 1
// baseline (2843.740 us; speedup 1.0000x reference)
//
#include <hip/hip_runtime.h>

#define PIX 4096
#define SCALE 0.25f

// ---- Wbig: block-lower-triangular cascade weight (512x512) ----
__global__ __launch_bounds__(256) void k_build_wbig(const float* __restrict__ vs_w,
                                                    float* __restrict__ Wbig) {
  int row = blockIdx.x;            // 0..511 ; i = head, d = out-ch within head
  int i = row >> 6, d = row & 63;
  for (int col = threadIdx.x; col < 512; col += 256) {
    int j = col >> 6, c = col & 63;
    Wbig[row * 512 + col] = (j <= i) ? vs_w[i * 4096 + d * 64 + c] : 0.f;
  }
}

// ---- GEMM: C[b][m,p] = sum_k W[m,k] * X[b][k,p] + bias[m] ----
// grid (PIX/64, M/64, B), block 256. K row-stride of W is 512 always.
__global__ __launch_bounds__(256) void k_gemm(const float* __restrict__ W,
                                              const float* __restrict__ X,
                                              const float* __restrict__ bias,
                                              float* __restrict__ C,
                                              int K, long xbs, long cbs, int triangular) {
  __shared__ __align__(16) float As[16][64];   // [k][m]
  __shared__ __align__(16) float Bs[16][64];   // [k][p]
  int b = blockIdx.z;
  int m0 = blockIdx.y * 64, p0 = blockIdx.x * 64;
  const float* Xb = X + (long)b * xbs;
  float* Cb = C + (long)b * cbs;
  int t = threadIdx.x;
  int tm = (t >> 4) << 2, tp = (t & 15) << 2;
  int lm = t >> 2, lk = (t & 3) << 2;          // W-tile load map
  int bk = t >> 4, bp = (t & 15) << 2;         // X-tile load map
  float acc[4][4] = {};
  int kend = triangular ? (m0 + 64) : K;
  for (int k0 = 0; k0 < kend; k0 += 16) {
    float4 wv = *(const float4*)&W[(long)(m0 + lm) * K + k0 + lk];
    As[lk + 0][lm] = wv.x; As[lk + 1][lm] = wv.y;
    As[lk + 2][lm] = wv.z; As[lk + 3][lm] = wv.w;
    *(float4*)&Bs[bk][bp] = *(const float4*)&Xb[(long)(k0 + bk) * PIX + p0 + bp];
    __syncthreads();
#pragma unroll
    for (int k = 0; k < 16; ++k) {
      float4 a = *(const float4*)&As[k][tm];
      float4 bb = *(const float4*)&Bs[k][tp];
      float av[4] = {a.x, a.y, a.z, a.w};
      float bv[4] = {bb.x, bb.y, bb.z, bb.w};
#pragma unroll
      for (int i = 0; i < 4; ++i)
#pragma unroll
        for (int j = 0; j < 4; ++j)
          acc[i][j] += av[i] * bv[j];
    }
    __syncthreads();
  }
#pragma unroll
  for (int i = 0; i < 4; ++i) {
    float bi = bias[m0 + tm + i];
    float4 o;
    o.x = acc[i][0] + bi; o.y = acc[i][1] + bi;
    o.z = acc[i][2] + bi; o.w = acc[i][3] + bi;
    *(float4*)&Cb[(long)(m0 + tm + i) * PIX + p0 + tp] = o;
  }
}

// ---- depthwise 5x5 SAME conv on q-half of feat ----
// grid (128, B), block 256
__global__ __launch_bounds__(256) void k_dwconv(const float* __restrict__ feat,
                                                const float* __restrict__ w,
                                                const float* __restrict__ bias,
                                                float* __restrict__ qconv) {
  __shared__ float tile[68][68];
  int c = blockIdx.x, b = blockIdx.y;
  const float* in = feat + ((long)b * 256 + c) * PIX;
  float wreg[25];
#pragma unroll
  for (int i = 0; i < 25; ++i) wreg[i] = w[c * 25 + i];
  float bi = bias[c];
  int t = threadIdx.x;
  for (int idx = t; idx < 68 * 68; idx += 256) {
    int y = idx / 68, xx = idx - y * 68;
    int h = y - 2, ww = xx - 2;
    float v = 0.f;
    if (h >= 0 && h < 64 && ww >= 0 && ww < 64) v = in[h * 64 + ww];
    tile[y][xx] = v;
  }
  __syncthreads();
  float* out = qconv + ((long)b * 128 + c) * PIX;
  int tx = (t & 15) << 2, ty = (t >> 4) << 2;
#pragma unroll
  for (int i = 0; i < 4; ++i) {
    float4 o;
    float* po = (float*)&o;
#pragma unroll
    for (int j = 0; j < 4; ++j) {
      float s = bi;
#pragma unroll
      for (int dy = 0; dy < 5; ++dy)
#pragma unroll
        for (int dx = 0; dx < 5; ++dx)
          s += wreg[dy * 5 + dx] * tile[ty + i + dy][tx + j + dx];
      po[j] = s;
    }
    *(float4*)&out[(ty + i) * 64 + tx] = o;
  }
}

// ---- 64x64 per-image transpose (optional relu) ----
// grid (B*nc), block 256. in image at ((b*ibs + ic0 + c))*PIX, out at (b*nc+c)*PIX
__global__ __launch_bounds__(256) void k_transpose(const float* __restrict__ in,
                                                   float* __restrict__ out,
                                                   int nc, int ibs, int ic0, int relu) {
  __shared__ float tile[64][65];
  int img = blockIdx.x;
  int b = img / nc, c = img - b * nc;
  const float* ip = in + ((long)b * ibs + ic0 + c) * PIX;
  float* op = out + (long)img * PIX;
  int t = threadIdx.x;
  int col = t & 63, r0 = t >> 6;
  for (int it = 0; it < 16; ++it) {
    int r = r0 + it * 4;
    tile[r][col] = ip[r * 64 + col];
  }
  __syncthreads();
  for (int it = 0; it < 16; ++it) {
    int r = r0 + it * 4;
    float v = tile[col][r];
    if (relu) v = fmaxf(v, 0.f);
    op[r * 64 + col] = v;
  }
}

// ---- attention scores + softmax ----
// grid (64, B): j = slab index. S[q,k] = SCALE*sum_c Q[c][q]K[c][k] + bias[idx[q,k]]
__global__ __launch_bounds__(256) void k_attn(const float* __restrict__ Q,
                                              const float* __restrict__ Kp,
                                              long qbs, long kbs,
                                              const float* __restrict__ bias,
                                              const int* __restrict__ idx,
                                              float* __restrict__ attn) {
  __shared__ __align__(16) float Qs[16][64];
  __shared__ __align__(16) float Ks[16][64];
  __shared__ float Ss[64][65];
  __shared__ float red[4][64];
  __shared__ float rowm[64], rows[64];
  int j = blockIdx.x, b = blockIdx.y;
  const float* Qb = Q + (long)b * qbs + j * 64;
  const float* Kb = Kp + (long)b * kbs + j * 64;
  int t = threadIdx.x;
  int tq = (t >> 4) << 2, tk = (t & 15) << 2;
  int lc = t >> 4, lp = (t & 15) << 2;
  float acc[4][4] = {};
  for (int c0 = 0; c0 < 128; c0 += 16) {
    *(float4*)&Qs[lc][lp] = *(const float4*)&Qb[(long)(c0 + lc) * PIX + lp];
    *(float4*)&Ks[lc][lp] = *(const float4*)&Kb[(long)(c0 + lc) * PIX + lp];
    __syncthreads();
#pragma unroll
    for (int c = 0; c < 16; ++c) {
      float4 a = *(const float4*)&Qs[c][tq];
      float4 bb = *(const float4*)&Ks[c][tk];
      float av[4] = {a.x, a.y, a.z, a.w};
      float bv[4] = {bb.x, bb.y, bb.z, bb.w};
#pragma unroll
      for (int i = 0; i < 4; ++i)
#pragma unroll
        for (int j2 = 0; j2 < 4; ++j2)
          acc[i][j2] += av[i] * bv[j2];
    }
    __syncthreads();
  }
#pragma unroll
  for (int i = 0; i < 4; ++i)
#pragma unroll
    for (int j2 = 0; j2 < 4; ++j2)
      Ss[tq + i][tk + j2] = acc[i][j2] * SCALE + bias[idx[(tq + i) * 64 + tk + j2]];
  __syncthreads();
  int row = t & 63, part = t >> 6;
  float m = -1e30f;
  for (int k = part * 16; k < part * 16 + 16; ++k) m = fmaxf(m, Ss[row][k]);
  red[part][row] = m;
  __syncthreads();
  if (t < 64) rowm[t] = fmaxf(fmaxf(red[0][t], red[1][t]), fmaxf(red[2][t], red[3][t]));
  __syncthreads();
  float mm = rowm[row];
  float s = 0.f;
  for (int k = part * 16; k < part * 16 + 16; ++k) s += __expf(Ss[row][k] - mm);
  red[part][row] = s;
  __syncthreads();
  if (t < 64) rows[t] = 1.f / (red[0][t] + red[1][t] + red[2][t] + red[3][t]);
  __syncthreads();
  float* ab = attn + ((long)b * 64 + j) * 4096;
  for (int ii = t; ii < 4096; ii += 256) {
    int r = ii >> 6, k = ii & 63;
    ab[ii] = __expf(Ss[r][k] - rowm[r]) * rows[r];
  }
}

// ---- apply attention along a slab: out[ch,q] = sum_k A[q,k] * V[ch,k] ----
// grid (64, B). Layouts: V/O at base + b*512*PIX + ch*PIX + j*64 + {k,q}
#define SWZ(row, k4) ((((k4) ^ ((row) >> 2)) & 15))
__global__ __launch_bounds__(256) void k_apply(const float* __restrict__ V,
                                               const float* __restrict__ A,
                                               float* __restrict__ O) {
  __shared__ __align__(16) float As[64][64];
  __shared__ __align__(16) float Vs[64][64];
  int j = blockIdx.x, b = blockIdx.y;
  int t = threadIdx.x;
  const float* Ab = A + ((long)b * 64 + j) * 4096;
  for (int ii = t; ii < 4096; ii += 256) {
    int q = ii >> 6, k = ii & 63;
    As[q][SWZ(q, k >> 2) * 4 + (k & 3)] = Ab[ii];
  }
  const float* Vb = V + (long)b * 512 * PIX + j * 64;
  float* Ob = O + (long)b * 512 * PIX + j * 64;
  int tq = (t & 15) << 2;       // q0
  int cl = (t >> 4) << 2;       // local ch0
  for (int chb = 0; chb < 512; chb += 64) {
    __syncthreads();            // previous compute done (and As ready on iter 0)
    for (int ii = t; ii < 4096; ii += 256) {
      int cc = ii >> 6, k = ii & 63;
      Vs[cc][SWZ(cc, k >> 2) * 4 + (k & 3)] = Vb[(long)(chb + cc) * PIX + k];
    }
    __syncthreads();
    float acc[4][4] = {};
#pragma unroll
    for (int k4 = 0; k4 < 16; ++k4) {
      float4 av[4], vv[4];
#pragma unroll
      for (int i = 0; i < 4; ++i) av[i] = *(const float4*)&As[tq + i][SWZ(tq + i, k4) * 4];
#pragma unroll
      for (int i = 0; i < 4; ++i) vv[i] = *(const float4*)&Vs[cl + i][SWZ(cl + i, k4) * 4];
#pragma unroll
      for (int ci = 0; ci < 4; ++ci)
#pragma unroll
        for (int qi = 0; qi < 4; ++qi)
          acc[ci][qi] += av[qi].x * vv[ci].x + av[qi].y * vv[ci].y +
                         av[qi].z * vv[ci].z + av[qi].w * vv[ci].w;
    }
#pragma unroll
    for (int ci = 0; ci < 4; ++ci) {
      float4 o = {acc[ci][0], acc[ci][1], acc[ci][2], acc[ci][3]};
      *(float4*)&Ob[(long)(chb + cl + ci) * PIX + tq] = o;
    }
  }
}

extern "C" void kernel_launch(void* const* d_in, const int* in_sizes, int n_in,
                              void* d_out, int out_size, void* d_ws, size_t ws_size,
                              hipStream_t stream) {
  const float* x      = (const float*)d_in[0];
  const float* qk_w   = (const float*)d_in[1];
  const float* qk_b   = (const float*)d_in[2];
  const float* dws_w  = (const float*)d_in[3];
  const float* dws_b  = (const float*)d_in[4];
  const float* vs_w   = (const float*)d_in[5];
  const float* vs_b   = (const float*)d_in[6];
  const float* proj_w = (const float*)d_in[7];
  const float* proj_b = (const float*)d_in[8];
  const float* bias_h = (const float*)d_in[9];
  const float* bias_w = (const float*)d_in[10];
  const int*   idx_h  = (const int*)d_in[11];
  const int*   idx_w  = (const int*)d_in[12];

  float* ws = (float*)d_ws;
  // Zone R1 (67,108,864 floats): feat+qT+kT -> V -> tT -> g (each lifetime disjoint)
  float* feat  = ws;                       // 33,554,432 floats (B,256,64,64)
  float* qT    = ws + 33554432;            // 16,777,216  (B,128,w,h)
  float* kT    = ws + 50331648;            // 16,777,216  (B,128,w,h)
  float* V     = ws;                       // 67,108,864  (B,512,h,w)
  float* tT    = ws;                       // 67,108,864  (B,512,w,h)
  float* g     = ws;                       // 67,108,864  (B,512,h,w), relu'd
  float* attnW = ws + 67108864;            //  8,388,608  (B,h,q,k)
  float* attnH = attnW + 8388608;          //  8,388,608  (B,w,q,k)
  float* qconv = attnH + 8388608;          // 16,777,216  (B,128,h,w)
  float* Wbig  = qconv + 16777216;         //    262,144
  float* tbuf = (float*)d_out;             // d_out doubles as scratch: t, then fT
  float* fT   = (float*)d_out;
  float* outp = (float*)d_out;

  k_build_wbig<<<512, 256, 0, stream>>>(vs_w, Wbig);
  // feat = qk_w @ x + qk_b   (B,256,PIX)
  k_gemm<<<dim3(64, 4, 32), 256, 0, stream>>>(qk_w, x, qk_b, feat,
                                              512, 512L * PIX, 256L * PIX, 0);
  k_dwconv<<<dim3(128, 32), 256, 0, stream>>>(feat, dws_w, dws_b, qconv);
  k_transpose<<<32 * 128, 256, 0, stream>>>(qconv, qT, 128, 128, 0, 0);
  k_transpose<<<32 * 128, 256, 0, stream>>>(feat, kT, 128, 256, 128, 0);
  // attn_w from (qconv, k-half of feat); attn_h from transposed copies
  k_attn<<<dim3(64, 32), 256, 0, stream>>>(qconv, feat + 128 * PIX,
                                           128L * PIX, 256L * PIX, bias_w, idx_w, attnW);
  k_attn<<<dim3(64, 32), 256, 0, stream>>>(qT, kT,
                                           128L * PIX, 128L * PIX, bias_h, idx_h, attnH);
  // V_all = Wbig @ x + vs_b (block-triangular K cut)
  k_gemm<<<dim3(64, 8, 32), 256, 0, stream>>>(Wbig, x, vs_b, V,
                                              512, 512L * PIX, 512L * PIX, 1);
  // t[b,ch,h,w] = sum_k attnW[b,h,w,k] V[b,ch,h,k]   (into d_out)
  k_apply<<<dim3(64, 32), 256, 0, stream>>>(V, attnW, tbuf);
  k_transpose<<<32 * 512, 256, 0, stream>>>(tbuf, tT, 512, 512, 0, 0);
  // fT[b,ch,w,h] = sum_k attnH[b,w,h,k] tT[b,ch,w,k] (into d_out)
  k_apply<<<dim3(64, 32), 256, 0, stream>>>(tT, attnH, fT);
  // g = relu(transpose back)
  k_transpose<<<32 * 512, 256, 0, stream>>>(fT, g, 512, 512, 0, 1);
  // out = proj_w @ g + proj_b
  k_gemm<<<dim3(64, 8, 32), 256, 0, stream>>>(proj_w, g, proj_b, outp,
                                              512, 512L * PIX, 512L * PIX, 0);
}

// Round 2
// 1408.663 us; speedup vs baseline: 2.0188x; 2.0188x over previous
//
#include <hip/hip_runtime.h>

#define PIX 4096
#define SCALE 0.25f

typedef short bf16x8 __attribute__((ext_vector_type(8)));
typedef float f32x4 __attribute__((ext_vector_type(4)));

__device__ inline unsigned short f2bf(float f) {
  unsigned int u = __float_as_uint(f);
  u += 0x7fffu + ((u >> 16) & 1u);
  return (unsigned short)(u >> 16);
}

__device__ inline void gload_lds16(const unsigned short* g, unsigned short* l) {
  __builtin_amdgcn_global_load_lds((const __attribute__((address_space(1))) void*)g,
                                   (__attribute__((address_space(3))) void*)l, 16, 0, 0);
}

// ---- elementwise fp32 -> bf16 ----
__global__ __launch_bounds__(256) void k_cvt(const float* __restrict__ in,
                                             unsigned short* __restrict__ out, int n) {
  int i = blockIdx.x * 256 + threadIdx.x;
  if (i < n) out[i] = f2bf(in[i]);
}

// ---- Wbig: block-lower-triangular cascade weight (512x512), bf16 ----
__global__ __launch_bounds__(256) void k_build_wbig(const float* __restrict__ vs_w,
                                                    unsigned short* __restrict__ Wbig) {
  int row = blockIdx.x;            // i = head, d = out-ch within head
  int i = row >> 6, d = row & 63;
  for (int col = threadIdx.x; col < 512; col += 256) {
    int j = col >> 6, c = col & 63;
    Wbig[row * 512 + col] = (j <= i) ? f2bf(vs_w[i * 4096 + d * 64 + c]) : (unsigned short)0;
  }
}

// ---- x [b][512][4096] fp32 -> xb [b][4096][512] bf16 (transpose+convert) ----
// grid (64, 8, 32) block 256
__global__ __launch_bounds__(256) void k_xt(const float* __restrict__ x,
                                            unsigned short* xb0, unsigned short* xb1) {
  __shared__ float tile[64][65];
  int b = blockIdx.z, k0 = blockIdx.y * 64, p0 = blockIdx.x * 64;
  const float* xp = x + ((size_t)b * 512 + k0) * PIX + p0;
  unsigned short* out = (b < 16) ? xb0 + (size_t)b * PIX * 512
                                 : xb1 + (size_t)(b - 16) * PIX * 512;
  int t = threadIdx.x;
  int r = t >> 4, c4 = (t & 15) << 2;
#pragma unroll
  for (int it = 0; it < 4; ++it) {
    float4 v = *(const float4*)&xp[(size_t)(r + it * 16) * PIX + c4];
    tile[r + it * 16][c4 + 0] = v.x; tile[r + it * 16][c4 + 1] = v.y;
    tile[r + it * 16][c4 + 2] = v.z; tile[r + it * 16][c4 + 3] = v.w;
  }
  __syncthreads();
  int pr = t >> 5, kk = (t & 31) << 1;
#pragma unroll
  for (int it = 0; it < 8; ++it) {
    int p = pr + it * 8;
    unsigned int val = (unsigned int)f2bf(tile[kk][p]) | ((unsigned int)f2bf(tile[kk + 1][p]) << 16);
    *(unsigned int*)&out[(size_t)(p0 + p) * 512 + k0 + kk] = val;
  }
}

// ---- fT [b][512][w*64+h] fp32 (split) -> gbt [b][h*64+w][512] bf16, with relu ----
// grid (64, 8, 32) block 256
__global__ __launch_bounds__(256) void k_gbt(const float* fq0, const float* fq1,
                                             unsigned short* __restrict__ gbt) {
  __shared__ float tile[64][65];
  int b = blockIdx.z, ch0 = blockIdx.y * 64, w = blockIdx.x;
  const float* f = (b < 16) ? fq0 + (size_t)b * 2097152 : fq1 + (size_t)(b - 16) * 2097152;
  const float* fp = f + (size_t)ch0 * PIX + w * 64;
  unsigned short* out = gbt + (size_t)b * 2097152;
  int t = threadIdx.x;
  int r = t >> 4, c4 = (t & 15) << 2;
#pragma unroll
  for (int it = 0; it < 4; ++it) {
    float4 v = *(const float4*)&fp[(size_t)(r + it * 16) * PIX + c4];
    tile[r + it * 16][c4 + 0] = v.x; tile[r + it * 16][c4 + 1] = v.y;
    tile[r + it * 16][c4 + 2] = v.z; tile[r + it * 16][c4 + 3] = v.w;
  }
  __syncthreads();
  int hr = t >> 5, kk = (t & 31) << 1;
#pragma unroll
  for (int it = 0; it < 8; ++it) {
    int h = hr + it * 8;
    float a = fmaxf(tile[kk][h], 0.f), bb = fmaxf(tile[kk + 1][h], 0.f);
    unsigned int val = (unsigned int)f2bf(a) | ((unsigned int)f2bf(bb) << 16);
    *(unsigned int*)&out[((size_t)(h * 64 + w)) * 512 + ch0 + kk] = val;
  }
}

// ---- MFMA GEMM: C[b][m][p] = sum_k A[m][k] * Bt[b][p][k] + bias[m] ----
// A: bf16 [M][512]; Bt: bf16 [nb][4096][512] split in two halves; C fp32 split.
// grid (32, M/128, 32), block 256 (4 waves, each 64x64 of the 128x128 tile)
__global__ __launch_bounds__(256) void k_mgemm(const unsigned short* __restrict__ A,
                                               const unsigned short* __restrict__ B0,
                                               const unsigned short* __restrict__ B1,
                                               const float* __restrict__ bias,
                                               float* C0, float* C1,
                                               int M, int tri) {
  __shared__ __align__(16) unsigned short As[128 * 32];
  __shared__ __align__(16) unsigned short Bs[128 * 32];
  int b = blockIdx.z;
  const unsigned short* Bb = (b < 16) ? B0 + (size_t)b * 2097152
                                      : B1 + (size_t)(b - 16) * 2097152;
  float* Cb = ((b < 16) ? C0 : C1) + (size_t)(b & 15) * M * PIX;
  int m0 = blockIdx.y * 128, p0 = blockIdx.x * 128;
  int t = threadIdx.x, wid = t >> 6, lane = t & 63;
  int wm = (wid >> 1) * 64, wn = (wid & 1) * 64;
  int lr = lane & 15, q = lane >> 4;
  f32x4 acc[4][4] = {};
  int kend = tri ? (m0 + 128) : 512;
  // staging maps: linear chunk L -> row r = L>>2, slot s = L&3; fetch global
  // chunk c = s ^ ((r>>1)&3) so LDS ends up XOR-swizzled (<=2-way conflicts).
  int L0 = wid * 64 + lane, r0 = L0 >> 2, c0 = (L0 & 3) ^ ((r0 >> 1) & 3);
  int L1 = (4 + wid) * 64 + lane, r1 = L1 >> 2, c1 = (L1 & 3) ^ ((r1 >> 1) & 3);
  const unsigned short* Ab = A + (size_t)m0 * 512;
  const unsigned short* Bp = Bb + (size_t)p0 * 512;
  size_t ga0 = (size_t)r0 * 512 + c0 * 8, ga1 = (size_t)r1 * 512 + c1 * 8;
  for (int k0 = 0; k0 < kend; k0 += 32) {
    gload_lds16(Ab + ga0 + k0, &As[wid * 512]);
    gload_lds16(Ab + ga1 + k0, &As[(4 + wid) * 512]);
    gload_lds16(Bp + ga0 + k0, &Bs[wid * 512]);
    gload_lds16(Bp + ga1 + k0, &Bs[(4 + wid) * 512]);
    __syncthreads();
    bf16x8 af[4], bf_[4];
#pragma unroll
    for (int mi = 0; mi < 4; ++mi) {
      int rr = wm + mi * 16 + lr;
      af[mi] = *(const bf16x8*)&As[rr * 32 + ((q ^ ((rr >> 1) & 3)) << 3)];
    }
#pragma unroll
    for (int ni = 0; ni < 4; ++ni) {
      int rr = wn + ni * 16 + lr;
      bf_[ni] = *(const bf16x8*)&Bs[rr * 32 + ((q ^ ((rr >> 1) & 3)) << 3)];
    }
#pragma unroll
    for (int mi = 0; mi < 4; ++mi)
#pragma unroll
      for (int ni = 0; ni < 4; ++ni)
        acc[mi][ni] = __builtin_amdgcn_mfma_f32_16x16x32_bf16(af[mi], bf_[ni], acc[mi][ni], 0, 0, 0);
    __syncthreads();
  }
#pragma unroll
  for (int mi = 0; mi < 4; ++mi) {
#pragma unroll
    for (int rr = 0; rr < 4; ++rr) {
      int m = m0 + wm + mi * 16 + q * 4 + rr;
      float bi = bias[m];
      float* crow = Cb + (size_t)m * PIX + p0 + wn;
#pragma unroll
      for (int ni = 0; ni < 4; ++ni)
        crow[ni * 16 + lr] = acc[mi][ni][rr] + bi;
    }
  }
}

// ---- depthwise 5x5 SAME conv on q-half of feat ---- grid (128, B)
__global__ __launch_bounds__(256) void k_dwconv(const float* __restrict__ feat,
                                                const float* __restrict__ w,
                                                const float* __restrict__ bias,
                                                float* __restrict__ qconv) {
  __shared__ float tile[68][68];
  int c = blockIdx.x, b = blockIdx.y;
  const float* in = feat + ((size_t)b * 256 + c) * PIX;
  float wreg[25];
#pragma unroll
  for (int i = 0; i < 25; ++i) wreg[i] = w[c * 25 + i];
  float bi = bias[c];
  int t = threadIdx.x;
  for (int idx = t; idx < 68 * 68; idx += 256) {
    int y = idx / 68, xx = idx - y * 68;
    int h = y - 2, ww = xx - 2;
    float v = 0.f;
    if (h >= 0 && h < 64 && ww >= 0 && ww < 64) v = in[h * 64 + ww];
    tile[y][xx] = v;
  }
  __syncthreads();
  float* out = qconv + ((size_t)b * 128 + c) * PIX;
  int tx = (t & 15) << 2, ty = (t >> 4) << 2;
#pragma unroll
  for (int i = 0; i < 4; ++i) {
    float4 o;
    float* po = (float*)&o;
#pragma unroll
    for (int j = 0; j < 4; ++j) {
      float s = bi;
#pragma unroll
      for (int dy = 0; dy < 5; ++dy)
#pragma unroll
        for (int dx = 0; dx < 5; ++dx)
          s += wreg[dy * 5 + dx] * tile[ty + i + dy][tx + j + dx];
      po[j] = s;
    }
    *(float4*)&out[(ty + i) * 64 + tx] = o;
  }
}

// ---- 64x64 per-image fp32 transpose ---- grid (nb*nc) block 256
__global__ __launch_bounds__(256) void k_transpose(const float* __restrict__ in,
                                                   float* __restrict__ out,
                                                   int nc, int ibs, int ic0) {
  __shared__ float tile[64][65];
  int img = blockIdx.x;
  int b = img / nc, c = img - b * nc;
  const float* ip = in + ((size_t)b * ibs + ic0 + c) * PIX;
  float* op = out + (size_t)img * PIX;
  int t = threadIdx.x;
  int col = t & 63, r0 = t >> 6;
  for (int it = 0; it < 16; ++it) {
    int r = r0 + it * 4;
    tile[r][col] = ip[r * 64 + col];
  }
  __syncthreads();
  for (int it = 0; it < 16; ++it) {
    int r = r0 + it * 4;
    op[r * 64 + col] = tile[col][r];
  }
}

// ---- attention scores + softmax ---- grid (64, B)
__global__ __launch_bounds__(256) void k_attn(const float* __restrict__ Q,
                                              const float* __restrict__ Kp,
                                              long qbs, long kbs,
                                              const float* __restrict__ bias,
                                              const int* __restrict__ idx,
                                              float* __restrict__ attn) {
  __shared__ __align__(16) float Qs[16][64];
  __shared__ __align__(16) float Ks[16][64];
  __shared__ float Ss[64][65];
  __shared__ float red[4][64];
  __shared__ float rowm[64], rows[64];
  int j = blockIdx.x, b = blockIdx.y;
  const float* Qb = Q + (size_t)b * qbs + j * 64;
  const float* Kb = Kp + (size_t)b * kbs + j * 64;
  int t = threadIdx.x;
  int tq = (t >> 4) << 2, tk = (t & 15) << 2;
  int lc = t >> 4, lp = (t & 15) << 2;
  float acc[4][4] = {};
  for (int c0 = 0; c0 < 128; c0 += 16) {
    *(float4*)&Qs[lc][lp] = *(const float4*)&Qb[(size_t)(c0 + lc) * PIX + lp];
    *(float4*)&Ks[lc][lp] = *(const float4*)&Kb[(size_t)(c0 + lc) * PIX + lp];
    __syncthreads();
#pragma unroll
    for (int c = 0; c < 16; ++c) {
      float4 a = *(const float4*)&Qs[c][tq];
      float4 bb = *(const float4*)&Ks[c][tk];
      float av[4] = {a.x, a.y, a.z, a.w};
      float bv[4] = {bb.x, bb.y, bb.z, bb.w};
#pragma unroll
      for (int i = 0; i < 4; ++i)
#pragma unroll
        for (int j2 = 0; j2 < 4; ++j2)
          acc[i][j2] += av[i] * bv[j2];
    }
    __syncthreads();
  }
#pragma unroll
  for (int i = 0; i < 4; ++i)
#pragma unroll
    for (int j2 = 0; j2 < 4; ++j2)
      Ss[tq + i][tk + j2] = acc[i][j2] * SCALE + bias[idx[(tq + i) * 64 + tk + j2]];
  __syncthreads();
  int row = t & 63, part = t >> 6;
  float m = -1e30f;
  for (int k = part * 16; k < part * 16 + 16; ++k) m = fmaxf(m, Ss[row][k]);
  red[part][row] = m;
  __syncthreads();
  if (t < 64) rowm[t] = fmaxf(fmaxf(red[0][t], red[1][t]), fmaxf(red[2][t], red[3][t]));
  __syncthreads();
  float mm = rowm[row];
  float s = 0.f;
  for (int k = part * 16; k < part * 16 + 16; ++k) s += __expf(Ss[row][k] - mm);
  red[part][row] = s;
  __syncthreads();
  if (t < 64) rows[t] = 1.f / (red[0][t] + red[1][t] + red[2][t] + red[3][t]);
  __syncthreads();
  float* ab = attn + ((size_t)b * 64 + j) * 4096;
  for (int ii = t; ii < 4096; ii += 256) {
    int r = ii >> 6, k = ii & 63;
    ab[ii] = __expf(Ss[r][k] - rowm[r]) * rows[r];
  }
}

// ---- apply attention along a slab, IN-PLACE: V[ch][j*64+q] = sum_k A[q,k] V[ch][j*64+k] ----
// grid (64, B). V split across two half-buffers, per-batch stride 512*PIX.
#define SWZ(row, k4) ((((k4) ^ ((row) >> 2)) & 15))
__global__ __launch_bounds__(256) void k_apply(float* V0, float* V1,
                                               const float* __restrict__ A) {
  __shared__ __align__(16) float As[64][64];
  __shared__ __align__(16) float Vs[64][64];
  int j = blockIdx.x, b = blockIdx.y;
  int t = threadIdx.x;
  const float* Ab = A + ((size_t)b * 64 + j) * 4096;
  for (int ii = t; ii < 4096; ii += 256) {
    int qq = ii >> 6, k = ii & 63;
    As[qq][SWZ(qq, k >> 2) * 4 + (k & 3)] = Ab[ii];
  }
  float* Vb = ((b < 16) ? V0 + (size_t)b * 512 * PIX : V1 + (size_t)(b - 16) * 512 * PIX) + j * 64;
  int tq = (t & 15) << 2;
  int cl = (t >> 4) << 2;
  for (int chb = 0; chb < 512; chb += 64) {
    __syncthreads();
    for (int ii = t; ii < 4096; ii += 256) {
      int cc = ii >> 6, k = ii & 63;
      Vs[cc][SWZ(cc, k >> 2) * 4 + (k & 3)] = Vb[(size_t)(chb + cc) * PIX + k];
    }
    __syncthreads();
    float acc[4][4] = {};
#pragma unroll
    for (int k4 = 0; k4 < 16; ++k4) {
      float4 av[4], vv[4];
#pragma unroll
      for (int i = 0; i < 4; ++i) av[i] = *(const float4*)&As[tq + i][SWZ(tq + i, k4) * 4];
#pragma unroll
      for (int i = 0; i < 4; ++i) vv[i] = *(const float4*)&Vs[cl + i][SWZ(cl + i, k4) * 4];
#pragma unroll
      for (int ci = 0; ci < 4; ++ci)
#pragma unroll
        for (int qi = 0; qi < 4; ++qi)
          acc[ci][qi] += av[qi].x * vv[ci].x + av[qi].y * vv[ci].y +
                         av[qi].z * vv[ci].z + av[qi].w * vv[ci].w;
    }
#pragma unroll
    for (int ci = 0; ci < 4; ++ci) {
      float4 o = {acc[ci][0], acc[ci][1], acc[ci][2], acc[ci][3]};
      *(float4*)&Vb[(size_t)(chb + cl + ci) * PIX + tq] = o;
    }
  }
}

extern "C" void kernel_launch(void* const* d_in, const int* in_sizes, int n_in,
                              void* d_out, int out_size, void* d_ws, size_t ws_size,
                              hipStream_t stream) {
  const float* x      = (const float*)d_in[0];
  const float* qk_w   = (const float*)d_in[1];
  const float* qk_b   = (const float*)d_in[2];
  const float* dws_w  = (const float*)d_in[3];
  const float* dws_b  = (const float*)d_in[4];
  const float* vs_w   = (const float*)d_in[5];
  const float* vs_b   = (const float*)d_in[6];
  const float* proj_w = (const float*)d_in[7];
  const float* proj_b = (const float*)d_in[8];
  const float* bias_h = (const float*)d_in[9];
  const float* bias_w = (const float*)d_in[10];
  const int*   idx_h  = (const int*)d_in[11];
  const int*   idx_w  = (const int*)d_in[12];

  float* ws = (float*)d_ws;
  float* dout = (float*)d_out;

  // ws layout (float units), total 84,213,760 floats = 337 MB:
  float* feat = ws;                                   // [0, 33.5M): feat -> V/t half A -> gbt
  float* PA   = ws;                                   //   V/t   batches 0-15
  unsigned short* gbt = (unsigned short*)ws;          //   [b][4096][512] bf16 (all 32 b)
  unsigned short* xbA = (unsigned short*)(ws + 33554432); // [33.5M,50.3M): xb batches 0-15
  float* QA   = ws + 33554432;                        // [33.5M,67.1M): tT/fT batches 0-15
  float* attnW = ws + 67108864;
  float* attnH = ws + 75497472;
  unsigned short* wbig_bf = (unsigned short*)(ws + 83886080);
  unsigned short* qkw_bf  = (unsigned short*)(ws + 84017152);
  unsigned short* pjw_bf  = (unsigned short*)(ws + 84082688);

  // d_out as scratch:
  float* qT    = dout;                                // [0,16.7M)
  float* kT    = dout + 16777216;                     // [16.7M,33.5M)
  float* PB    = dout;                                // V/t batches 16-31 (over qT/kT)
  float* qconv = dout + 33554432;                     // [33.5M,50.3M)
  float* QB    = dout + 33554432;                     // tT/fT batches 16-31
  unsigned short* xbB = (unsigned short*)(dout + 50331648); // [50.3M,67.1M)

  // weights -> bf16
  k_cvt<<<dim3(512), 256, 0, stream>>>(qk_w, qkw_bf, 131072);
  k_cvt<<<dim3(1024), 256, 0, stream>>>(proj_w, pjw_bf, 262144);
  k_build_wbig<<<512, 256, 0, stream>>>(vs_w, wbig_bf);
  // xb = x^T bf16
  k_xt<<<dim3(64, 8, 32), 256, 0, stream>>>(x, xbA, xbB);
  // feat = qk_w @ x + qk_b
  k_mgemm<<<dim3(32, 2, 32), 256, 0, stream>>>(qkw_bf, xbA, xbB, qk_b,
                                               feat, feat + 16777216, 256, 0);
  k_dwconv<<<dim3(128, 32), 256, 0, stream>>>(feat, dws_w, dws_b, qconv);
  k_transpose<<<32 * 128, 256, 0, stream>>>(qconv, qT, 128, 128, 0);
  k_transpose<<<32 * 128, 256, 0, stream>>>(feat, kT, 128, 256, 128);
  k_attn<<<dim3(64, 32), 256, 0, stream>>>(qconv, feat + 128 * PIX,
                                           128L * PIX, 256L * PIX, bias_w, idx_w, attnW);
  k_attn<<<dim3(64, 32), 256, 0, stream>>>(qT, kT,
                                           128L * PIX, 128L * PIX, bias_h, idx_h, attnH);
  // V = Wbig @ x + vs_b (triangular), split PA/PB
  k_mgemm<<<dim3(32, 4, 32), 256, 0, stream>>>(wbig_bf, xbA, xbB, vs_b,
                                               PA, PB, 512, 1);
  // t = attnW ⊙ V  (in place)
  k_apply<<<dim3(64, 32), 256, 0, stream>>>(PA, PB, attnW);
  // tT = transpose(t)  (both halves)
  k_transpose<<<16 * 512, 256, 0, stream>>>(PA, QA, 512, 512, 0);
  k_transpose<<<16 * 512, 256, 0, stream>>>(PB, QB, 512, 512, 0);
  // fT = attnH ⊙ tT (in place)
  k_apply<<<dim3(64, 32), 256, 0, stream>>>(QA, QB, attnH);
  // gbt = relu(fT)^T in bf16 [b][p=h*64+w][ch]
  k_gbt<<<dim3(64, 8, 32), 256, 0, stream>>>(QA, QB, gbt);
  // out = proj_w @ g + proj_b
  k_mgemm<<<dim3(32, 4, 32), 256, 0, stream>>>(pjw_bf, gbt, gbt + 33554432, proj_b,
                                               dout, dout + 33554432, 512, 0);
}

// Round 3
// 824.350 us; speedup vs baseline: 3.4497x; 1.7088x over previous
//
#include <hip/hip_runtime.h>

#define PIX 4096
#define SCALE 0.25f

typedef _Float16 f16x8 __attribute__((ext_vector_type(8)));
typedef float f32x4 __attribute__((ext_vector_type(4)));

__device__ inline void gload_lds16(const _Float16* g, _Float16* l) {
  __builtin_amdgcn_global_load_lds((const __attribute__((address_space(1))) void*)g,
                                   (__attribute__((address_space(3))) void*)l, 16, 0, 0);
}

// ---- elementwise fp32 -> fp16 ----
__global__ __launch_bounds__(256) void k_cvt(const float* __restrict__ in,
                                             _Float16* __restrict__ out, int n) {
  int i = blockIdx.x * 256 + threadIdx.x;
  if (i < n) out[i] = (_Float16)in[i];
}

// ---- Wbig: block-lower-triangular cascade weight (512x512), fp16 ----
__global__ __launch_bounds__(256) void k_build_wbig(const float* __restrict__ vs_w,
                                                    _Float16* __restrict__ Wbig) {
  int row = blockIdx.x;            // i = head, d = out-ch within head
  int i = row >> 6, d = row & 63;
  for (int col = threadIdx.x; col < 512; col += 256) {
    int j = col >> 6, c = col & 63;
    Wbig[row * 512 + col] = (j <= i) ? (_Float16)vs_w[i * 4096 + d * 64 + c] : (_Float16)0;
  }
}

// ---- x [b][512][4096] fp32 -> xh [b][4096][512] fp16 ---- grid (64,8,32)
__global__ __launch_bounds__(256) void k_xt(const float* __restrict__ x,
                                            _Float16* __restrict__ xh) {
  __shared__ float tile[64][65];
  int b = blockIdx.z, k0 = blockIdx.y * 64, p0 = blockIdx.x * 64;
  const float* xp = x + ((size_t)b * 512 + k0) * PIX + p0;
  _Float16* out = xh + (size_t)b * PIX * 512;
  int t = threadIdx.x;
  int r = t >> 4, c4 = (t & 15) << 2;
#pragma unroll
  for (int it = 0; it < 4; ++it) {
    float4 v = *(const float4*)&xp[(size_t)(r + it * 16) * PIX + c4];
    tile[r + it * 16][c4 + 0] = v.x; tile[r + it * 16][c4 + 1] = v.y;
    tile[r + it * 16][c4 + 2] = v.z; tile[r + it * 16][c4 + 3] = v.w;
  }
  __syncthreads();
  int pr = t >> 5, kk = (t & 31) << 1;
#pragma unroll
  for (int it = 0; it < 8; ++it) {
    int p = pr + it * 8;
    union { _Float16 h[2]; unsigned int u; } pk;
    pk.h[0] = (_Float16)tile[kk][p]; pk.h[1] = (_Float16)tile[kk + 1][p];
    *(unsigned int*)&out[(size_t)(p0 + p) * 512 + k0 + kk] = pk.u;
  }
}

// ---- MFMA GEMM: C[b][m][p] = sum_k A[m][k] * B[b][p][k] + bias[m] ----
// A fp16 [M][512]; B fp16 [32][4096][512]; out fp32 C or fp16 H.
// grid (32, M/128, 32), block 256 (4 waves, each 64x64 of the 128x128 tile)
__global__ __launch_bounds__(256) void k_mgemm(const _Float16* __restrict__ A,
                                               const _Float16* __restrict__ B,
                                               const float* __restrict__ bias,
                                               float* C, _Float16* H,
                                               int M, int tri, int out16) {
  __shared__ __align__(16) _Float16 As[128 * 32];
  __shared__ __align__(16) _Float16 Bs[128 * 32];
  int b = blockIdx.z;
  const _Float16* Bb = B + (size_t)b * 2097152;
  int m0 = blockIdx.y * 128, p0 = blockIdx.x * 128;
  int t = threadIdx.x, wid = t >> 6, lane = t & 63;
  int wm = (wid >> 1) * 64, wn = (wid & 1) * 64;
  int lr = lane & 15, q = lane >> 4;
  f32x4 acc[4][4] = {};
  int kend = tri ? (m0 + 128) : 512;
  int L0 = wid * 64 + lane, r0 = L0 >> 2, c0 = (L0 & 3) ^ ((r0 >> 1) & 3);
  int L1 = (4 + wid) * 64 + lane, r1 = L1 >> 2, c1 = (L1 & 3) ^ ((r1 >> 1) & 3);
  const _Float16* Ab = A + (size_t)m0 * 512;
  const _Float16* Bp = Bb + (size_t)p0 * 512;
  size_t ga0 = (size_t)r0 * 512 + c0 * 8, ga1 = (size_t)r1 * 512 + c1 * 8;
  for (int k0 = 0; k0 < kend; k0 += 32) {
    gload_lds16(Ab + ga0 + k0, &As[wid * 512]);
    gload_lds16(Ab + ga1 + k0, &As[(4 + wid) * 512]);
    gload_lds16(Bp + ga0 + k0, &Bs[wid * 512]);
    gload_lds16(Bp + ga1 + k0, &Bs[(4 + wid) * 512]);
    __syncthreads();
    f16x8 af[4], bf_[4];
#pragma unroll
    for (int mi = 0; mi < 4; ++mi) {
      int rr = wm + mi * 16 + lr;
      af[mi] = *(const f16x8*)&As[rr * 32 + ((q ^ ((rr >> 1) & 3)) << 3)];
    }
#pragma unroll
    for (int ni = 0; ni < 4; ++ni) {
      int rr = wn + ni * 16 + lr;
      bf_[ni] = *(const f16x8*)&Bs[rr * 32 + ((q ^ ((rr >> 1) & 3)) << 3)];
    }
#pragma unroll
    for (int mi = 0; mi < 4; ++mi)
#pragma unroll
      for (int ni = 0; ni < 4; ++ni)
        acc[mi][ni] = __builtin_amdgcn_mfma_f32_16x16x32_f16(af[mi], bf_[ni], acc[mi][ni], 0, 0, 0);
    __syncthreads();
  }
#pragma unroll
  for (int mi = 0; mi < 4; ++mi) {
#pragma unroll
    for (int rr = 0; rr < 4; ++rr) {
      int m = m0 + wm + mi * 16 + q * 4 + rr;
      float bi = bias[m];
      size_t base = ((size_t)b * M + m) * PIX + p0 + wn;
      if (out16) {
        _Float16* crow = H + base;
#pragma unroll
        for (int ni = 0; ni < 4; ++ni)
          crow[ni * 16 + lr] = (_Float16)(acc[mi][ni][rr] + bi);
      } else {
        float* crow = C + base;
#pragma unroll
        for (int ni = 0; ni < 4; ++ni)
          crow[ni * 16 + lr] = acc[mi][ni][rr] + bi;
      }
    }
  }
}

// ---- depthwise 5x5 SAME conv on q-half of feat ---- grid (128, B)
__global__ __launch_bounds__(256) void k_dwconv(const float* __restrict__ feat,
                                                const float* __restrict__ w,
                                                const float* __restrict__ bias,
                                                float* __restrict__ qconv) {
  __shared__ float tile[68][68];
  int c = blockIdx.x, b = blockIdx.y;
  const float* in = feat + ((size_t)b * 256 + c) * PIX;
  float wreg[25];
#pragma unroll
  for (int i = 0; i < 25; ++i) wreg[i] = w[c * 25 + i];
  float bi = bias[c];
  int t = threadIdx.x;
  for (int idx = t; idx < 68 * 68; idx += 256) {
    int y = idx / 68, xx = idx - y * 68;
    int h = y - 2, ww = xx - 2;
    float v = 0.f;
    if (h >= 0 && h < 64 && ww >= 0 && ww < 64) v = in[h * 64 + ww];
    tile[y][xx] = v;
  }
  __syncthreads();
  float* out = qconv + ((size_t)b * 128 + c) * PIX;
  int tx = (t & 15) << 2, ty = (t >> 4) << 2;
#pragma unroll
  for (int i = 0; i < 4; ++i) {
    float4 o;
    float* po = (float*)&o;
#pragma unroll
    for (int j = 0; j < 4; ++j) {
      float s = bi;
#pragma unroll
      for (int dy = 0; dy < 5; ++dy)
#pragma unroll
        for (int dx = 0; dx < 5; ++dx)
          s += wreg[dy * 5 + dx] * tile[ty + i + dy][tx + j + dx];
      po[j] = s;
    }
    *(float4*)&out[(ty + i) * 64 + tx] = o;
  }
}

// ---- 64x64 per-image fp32 transpose ---- grid (nb*nc) block 256
__global__ __launch_bounds__(256) void k_transpose(const float* __restrict__ in,
                                                   float* __restrict__ out,
                                                   int nc, int ibs, int ic0) {
  __shared__ float tile[64][65];
  int img = blockIdx.x;
  int b = img / nc, c = img - b * nc;
  const float* ip = in + ((size_t)b * ibs + ic0 + c) * PIX;
  float* op = out + (size_t)img * PIX;
  int t = threadIdx.x;
  int col = t & 63, r0 = t >> 6;
  for (int it = 0; it < 16; ++it) {
    int r = r0 + it * 4;
    tile[r][col] = ip[r * 64 + col];
  }
  __syncthreads();
  for (int it = 0; it < 16; ++it) {
    int r = r0 + it * 4;
    op[r * 64 + col] = tile[col][r];
  }
}

// ---- 64x64 per-image fp16 transpose ---- grid (nb*nc) block 256
__global__ __launch_bounds__(256) void k_t16(const _Float16* __restrict__ in,
                                             _Float16* __restrict__ out) {
  __shared__ _Float16 tile[64][65];
  int img = blockIdx.x;
  const _Float16* ip = in + (size_t)img * PIX;
  _Float16* op = out + (size_t)img * PIX;
  int t = threadIdx.x;
  int col = t & 63, r0 = t >> 6;
  for (int it = 0; it < 16; ++it) {
    int r = r0 + it * 4;
    tile[r][col] = ip[r * 64 + col];
  }
  __syncthreads();
  for (int it = 0; it < 16; ++it) {
    int r = r0 + it * 4;
    op[r * 64 + col] = tile[col][r];
  }
}

// ---- fT fp16 [b][512][w*64+h] -> g fp16 [b][h*64+w][512] with relu ---- grid (64,8,32)
__global__ __launch_bounds__(256) void k_gbt(const _Float16* __restrict__ f,
                                             _Float16* __restrict__ g) {
  __shared__ _Float16 tile[64][65];
  int w = blockIdx.x, ch0 = blockIdx.y * 64, b = blockIdx.z;
  const _Float16* fp = f + ((size_t)b * 512 + ch0) * PIX + w * 64;
  _Float16* gp = g + (size_t)b * PIX * 512 + ch0;
  int t = threadIdx.x;
  int col = t & 63, r0 = t >> 6;
  for (int it = 0; it < 16; ++it) {
    int r = r0 + it * 4;
    _Float16 v = fp[(size_t)r * PIX + col];
    tile[r][col] = v > (_Float16)0 ? v : (_Float16)0;
  }
  __syncthreads();
  for (int it = 0; it < 16; ++it) {
    int h = r0 * 16 + it;
    gp[((size_t)h * 64 + w) * 512 + col] = tile[col][h];
  }
}

// ---- attention scores + softmax (fp32 in, fp32 out) ---- grid (64, B)
__global__ __launch_bounds__(256) void k_attn(const float* __restrict__ Q,
                                              const float* __restrict__ Kp,
                                              long qbs, long kbs,
                                              const float* __restrict__ bias,
                                              const int* __restrict__ idx,
                                              float* __restrict__ attn) {
  __shared__ __align__(16) float Qs[16][64];
  __shared__ __align__(16) float Ks[16][64];
  __shared__ float Ss[64][65];
  __shared__ float red[4][64];
  __shared__ float rowm[64], rows[64];
  int j = blockIdx.x, b = blockIdx.y;
  const float* Qb = Q + (size_t)b * qbs + j * 64;
  const float* Kb = Kp + (size_t)b * kbs + j * 64;
  int t = threadIdx.x;
  int tq = (t >> 4) << 2, tk = (t & 15) << 2;
  int lc = t >> 4, lp = (t & 15) << 2;
  float acc[4][4] = {};
  for (int c0 = 0; c0 < 128; c0 += 16) {
    *(float4*)&Qs[lc][lp] = *(const float4*)&Qb[(size_t)(c0 + lc) * PIX + lp];
    *(float4*)&Ks[lc][lp] = *(const float4*)&Kb[(size_t)(c0 + lc) * PIX + lp];
    __syncthreads();
#pragma unroll
    for (int c = 0; c < 16; ++c) {
      float4 a = *(const float4*)&Qs[c][tq];
      float4 bb = *(const float4*)&Ks[c][tk];
      float av[4] = {a.x, a.y, a.z, a.w};
      float bv[4] = {bb.x, bb.y, bb.z, bb.w};
#pragma unroll
      for (int i = 0; i < 4; ++i)
#pragma unroll
        for (int j2 = 0; j2 < 4; ++j2)
          acc[i][j2] += av[i] * bv[j2];
    }
    __syncthreads();
  }
#pragma unroll
  for (int i = 0; i < 4; ++i)
#pragma unroll
    for (int j2 = 0; j2 < 4; ++j2)
      Ss[tq + i][tk + j2] = acc[i][j2] * SCALE + bias[idx[(tq + i) * 64 + tk + j2]];
  __syncthreads();
  int row = t & 63, part = t >> 6;
  float m = -1e30f;
  for (int k = part * 16; k < part * 16 + 16; ++k) m = fmaxf(m, Ss[row][k]);
  red[part][row] = m;
  __syncthreads();
  if (t < 64) rowm[t] = fmaxf(fmaxf(red[0][t], red[1][t]), fmaxf(red[2][t], red[3][t]));
  __syncthreads();
  float mm = rowm[row];
  float s = 0.f;
  for (int k = part * 16; k < part * 16 + 16; ++k) s += __expf(Ss[row][k] - mm);
  red[part][row] = s;
  __syncthreads();
  if (t < 64) rows[t] = 1.f / (red[0][t] + red[1][t] + red[2][t] + red[3][t]);
  __syncthreads();
  float* ab = attn + ((size_t)b * 64 + j) * 4096;
  for (int ii = t; ii < 4096; ii += 256) {
    int r = ii >> 6, k = ii & 63;
    ab[ii] = __expf(Ss[r][k] - rowm[r]) * rows[r];
  }
}

// ---- MFMA attention apply, IN-PLACE on fp16 V ----
// grid (64 j, 32 b): V[ch][j*64+q] = sum_k A[b,j][q,k] * V[ch][j*64+k], ch=0..511
__global__ __launch_bounds__(256) void k_mapply(_Float16* V, const float* __restrict__ A) {
  __shared__ __align__(16) _Float16 As[64][64];
  __shared__ __align__(16) _Float16 Vs[64][64];
  int j = blockIdx.x, b = blockIdx.y;
  int t = threadIdx.x, wid = t >> 6, lane = t & 63;
  int lr = lane & 15, q4 = lane >> 4;
  const float* Ab = A + ((size_t)b * 64 + j) * 4096;
  for (int ii = t; ii < 4096; ii += 256) {
    int r = ii >> 6, k = ii & 63;
    As[r][(((k >> 3) ^ (r & 7)) << 3) + (k & 7)] = (_Float16)Ab[ii];
  }
  _Float16* Vb = V + (size_t)b * 512 * PIX + j * 64;
  __syncthreads();
  // hoist attn fragments (B-operand): bfr[ni][kk]
  f16x8 bfr[4][2];
#pragma unroll
  for (int ni = 0; ni < 4; ++ni)
#pragma unroll
    for (int kk = 0; kk < 2; ++kk) {
      int rr = ni * 16 + lr;
      bfr[ni][kk] = *(const f16x8*)&As[rr][(((kk * 4 + q4) ^ (rr & 7)) << 3)];
    }
  int fr = t >> 3, fc = t & 7;   // fill/drain map: rows fr, fr+32; 16B chunk fc
  for (int chb = 0; chb < 512; chb += 64) {
    *(f16x8*)&Vs[fr][((fc ^ (fr & 7)) << 3)] =
        *(const f16x8*)&Vb[(size_t)(chb + fr) * PIX + fc * 8];
    *(f16x8*)&Vs[fr + 32][((fc ^ ((fr + 32) & 7)) << 3)] =
        *(const f16x8*)&Vb[(size_t)(chb + fr + 32) * PIX + fc * 8];
    __syncthreads();
    f32x4 acc[4] = {};
#pragma unroll
    for (int kk = 0; kk < 2; ++kk) {
      int rr = wid * 16 + lr;
      f16x8 af = *(const f16x8*)&Vs[rr][(((kk * 4 + q4) ^ (rr & 7)) << 3)];
#pragma unroll
      for (int ni = 0; ni < 4; ++ni)
        acc[ni] = __builtin_amdgcn_mfma_f32_16x16x32_f16(af, bfr[ni][kk], acc[ni], 0, 0, 0);
    }
    __syncthreads();             // all frag reads done before restage overwrites
#pragma unroll
    for (int ni = 0; ni < 4; ++ni)
#pragma unroll
      for (int rr = 0; rr < 4; ++rr)
        Vs[wid * 16 + q4 * 4 + rr][ni * 16 + lr] = (_Float16)acc[ni][rr];
    __syncthreads();
    *(float4*)&Vb[(size_t)(chb + fr) * PIX + fc * 8] = *(const float4*)&Vs[fr][fc * 8];
    *(float4*)&Vb[(size_t)(chb + fr + 32) * PIX + fc * 8] = *(const float4*)&Vs[fr + 32][fc * 8];
    __syncthreads();             // drain reads done before next fill
  }
}

extern "C" void kernel_launch(void* const* d_in, const int* in_sizes, int n_in,
                              void* d_out, int out_size, void* d_ws, size_t ws_size,
                              hipStream_t stream) {
  const float* x      = (const float*)d_in[0];
  const float* qk_w   = (const float*)d_in[1];
  const float* qk_b   = (const float*)d_in[2];
  const float* dws_w  = (const float*)d_in[3];
  const float* dws_b  = (const float*)d_in[4];
  const float* vs_w   = (const float*)d_in[5];
  const float* vs_b   = (const float*)d_in[6];
  const float* proj_w = (const float*)d_in[7];
  const float* proj_b = (const float*)d_in[8];
  const float* bias_h = (const float*)d_in[9];
  const float* bias_w = (const float*)d_in[10];
  const int*   idx_h  = (const int*)d_in[11];
  const int*   idx_w  = (const int*)d_in[12];

  float* ws = (float*)d_ws;
  float* dout = (float*)d_out;

  // ws (float units), total 84,213,760 floats = 337 MB:
  _Float16* xh    = (_Float16*)ws;               // [0, 33.5M fl): x^T fp16 -> later ght
  float*    feat  = ws + 33554432;               // [33.5M, 67.1M fl) fp32
  float*    attnW = ws + 67108864;               // 8,388,608 fl
  float*    attnH = ws + 75497472;               // 8,388,608 fl
  _Float16* qkw_h  = (_Float16*)(ws + 83886080); // 131,072 halves
  _Float16* wbig_h = (_Float16*)(ws + 83951616); // 262,144 halves
  _Float16* pjw_h  = (_Float16*)(ws + 84082688); // 262,144 halves -> ends 84,213,760 fl
  _Float16* ght = xh;                            // reuse after V-mgemm

  // d_out phase scratch:
  float*    qconv = dout;                        // [0, 16.7M fl)
  float*    qT    = dout + 16777216;             // [16.7M, 33.5M fl)
  float*    kT    = dout + 33554432;             // [33.5M, 50.3M fl)
  _Float16* Vh    = (_Float16*)dout;             // [0, 33.5M fl) as 67.1M halves
  _Float16* tTh   = (_Float16*)(dout + 33554432);// [33.5M, 67.1M fl)

  k_cvt<<<dim3(512), 256, 0, stream>>>(qk_w, qkw_h, 131072);
  k_cvt<<<dim3(1024), 256, 0, stream>>>(proj_w, pjw_h, 262144);
  k_build_wbig<<<512, 256, 0, stream>>>(vs_w, wbig_h);
  k_xt<<<dim3(64, 8, 32), 256, 0, stream>>>(x, xh);
  // feat = qk_w @ x + qk_b (fp32 out)
  k_mgemm<<<dim3(32, 2, 32), 256, 0, stream>>>(qkw_h, xh, qk_b, feat, nullptr, 256, 0, 0);
  k_dwconv<<<dim3(128, 32), 256, 0, stream>>>(feat, dws_w, dws_b, qconv);
  k_transpose<<<32 * 128, 256, 0, stream>>>(qconv, qT, 128, 128, 0);
  k_transpose<<<32 * 128, 256, 0, stream>>>(feat, kT, 128, 256, 128);
  k_attn<<<dim3(64, 32), 256, 0, stream>>>(qconv, feat + 128 * PIX,
                                           128L * PIX, 256L * PIX, bias_w, idx_w, attnW);
  k_attn<<<dim3(64, 32), 256, 0, stream>>>(qT, kT,
                                           128L * PIX, 128L * PIX, bias_h, idx_h, attnH);
  // V = Wbig @ x + vs_b (triangular, fp16 out) -> d_out region
  k_mgemm<<<dim3(32, 4, 32), 256, 0, stream>>>(wbig_h, xh, vs_b, nullptr, Vh, 512, 1, 1);
  // t = attnW ⊙ V (in place, MFMA fp16)
  k_mapply<<<dim3(64, 32), 256, 0, stream>>>(Vh, attnW);
  // tT = transpose(t) fp16
  k_t16<<<32 * 512, 256, 0, stream>>>(Vh, tTh);
  // fT = attnH ⊙ tT (in place)
  k_mapply<<<dim3(64, 32), 256, 0, stream>>>(tTh, attnH);
  // ght = relu(fT)^T fp16 [b][p=h*64+w][ch]
  k_gbt<<<dim3(64, 8, 32), 256, 0, stream>>>(tTh, ght);
  // out = proj_w @ g + proj_b (fp32 out)
  k_mgemm<<<dim3(32, 4, 32), 256, 0, stream>>>(pjw_h, ght, proj_b, dout, nullptr, 512, 0, 0);
}